// Round 10
// baseline (330.367 us; speedup 1.0000x reference)
//
#include <hip/hip_runtime.h>
#include <hip/hip_fp16.h>

#define B_ 256
#define D_ 1024
#define N_ 200000
#define K_ 64
#define SHIFT_ 24.0f
#define NCHUNK 3125   // N_/64 exactly
#define SL_ 8         // K3a G-slices

typedef short short8 __attribute__((ext_vector_type(8)));
typedef _Float16 f16x8 __attribute__((ext_vector_type(8)));
typedef float f32x4 __attribute__((ext_vector_type(4)));

__device__ __forceinline__ unsigned f2bf(float x) {
  unsigned u = __float_as_uint(x);
  return (u + 0x7fffu + ((u >> 16) & 1u)) >> 16;
}
__device__ __forceinline__ unsigned pack2(float a, float b) {
  return f2bf(a) | (f2bf(b) << 16);
}
__device__ __forceinline__ float bf2f(unsigned short u) {
  return __uint_as_float(((unsigned)u) << 16);
}
__device__ __forceinline__ unsigned f2h(float x) {  // fp16 bits, RNE
  return (unsigned)__half_as_ushort(__float2half(x));
}
__device__ __forceinline__ f32x4 mfma16b(int4 a, int4 b, f32x4 c) {  // bf16
  return __builtin_amdgcn_mfma_f32_16x16x32_bf16(
      __builtin_bit_cast(short8, a), __builtin_bit_cast(short8, b), c, 0, 0, 0);
}
__device__ __forceinline__ f32x4 mfma16h(int4 a, int4 b, f32x4 c) {  // fp16
  return __builtin_amdgcn_mfma_f32_16x16x32_f16(
      __builtin_bit_cast(f16x8, a), __builtin_bit_cast(f16x8, b), c, 0, 0, 0);
}
__device__ __forceinline__ int p8hash(int k) { return ((k >> 3) ^ k) & 7; }

// ---------------------------------------------------------------------------
// K1: cue_outer[b][k] = sum_d cue[b][d] * w_cue[k][d]  (frozen)
// ---------------------------------------------------------------------------
__global__ __launch_bounds__(256) void k1_cueproj(
    const float* __restrict__ cue, const float* __restrict__ wcue,
    float* __restrict__ couter) {
  const int b    = blockIdx.x;
  const int tid  = threadIdx.x;
  const int w    = tid >> 6;
  const int lane = tid & 63;

  __shared__ float part[4][64][65];
  __shared__ float red[4][64];

  const float4 creg =
      *(const float4*)(cue + (size_t)b * D_ + w * 256 + lane * 4);
  const float* wbase = wcue + w * 256 + lane * 4;

#pragma unroll 8
  for (int k = 0; k < 64; ++k) {
    const float4 wv = *(const float4*)(wbase + (size_t)k * D_);
    part[w][k][lane] =
        creg.x * wv.x + creg.y * wv.y + creg.z * wv.z + creg.w * wv.w;
  }
  __syncthreads();

  const int k  = tid & 63;
  const int wq = tid >> 6;
  float a = 0.f;
#pragma unroll 8
  for (int j = 0; j < 64; ++j) a += part[wq][k][j];
  red[wq][k] = a;
  __syncthreads();
  if (tid < 64) {
    couter[b * K_ + tid] =
        red[0][tid] + red[1][tid] + red[2][tid] + red[3][tid];
  }
}

// ---------------------------------------------------------------------------
// K2: MFMA flash-attention. LDS diet (38.4 KB -> 4 blocks/CU): sh_E is a
// per-wave 64x40 n-HALF buffer; GEMM2 for n-half h runs right after GEMM1
// tiles t=2h,2h+1 (interleaves exp-VALU with MFMA). All LDS in one union;
// epilogue S-staging overlays it (after barrier, once per block).
// ---------------------------------------------------------------------------
__global__ __launch_bounds__(256, 4) void k2_attend(
    const float* __restrict__ slot, const float* __restrict__ prio,
    const float* __restrict__ couter, unsigned short* __restrict__ Spart,
    float* __restrict__ Zpart, int G) {
  // union: sh_h[64*72] | sh_T[64*64] | sh_E[4][64*40] | sh_p[64]  = 38400 B
  // epilogue staging view: [4][64][72] = 36864 B (overlays everything)
  __shared__ __align__(16) unsigned short sh_all[19200];
  unsigned short* const sh_h = sh_all;           // 4608 shorts
  unsigned short* const sh_T = sh_all + 4608;    // 4096 shorts
  unsigned short* const sh_E = sh_all + 8704;    // 10240 shorts (4 x 2560)
  float* const sh_p = (float*)(sh_all + 18944);  // 64 floats

  const int tid = threadIdx.x;
  const int g   = blockIdx.x;
  const int l   = tid & 63;
  const int w   = tid >> 6;
  const int c16 = l & 15;
  const int q   = l >> 4;

  // Q fragments (fp16), loaded once
  int4 qf[4][2];
#pragma unroll
  for (int bt = 0; bt < 4; ++bt) {
#pragma unroll
    for (int s = 0; s < 2; ++s) {
      const float* qp =
          couter + (size_t)(w * 64 + bt * 16 + c16) * K_ + s * 32 + q * 8;
      float4 va = *(const float4*)qp;
      float4 vb = *(const float4*)(qp + 4);
      qf[bt][s] = make_int4(
          (int)(f2h(va.x) | (f2h(va.y) << 16)),
          (int)(f2h(va.z) | (f2h(va.w) << 16)),
          (int)(f2h(vb.x) | (f2h(vb.y) << 16)),
          (int)(f2h(vb.z) | (f2h(vb.w) << 16)));
    }
  }

  f32x4 S[4][4];
#pragma unroll
  for (int a = 0; a < 4; ++a)
#pragma unroll
    for (int b = 0; b < 4; ++b) S[a][b] = (f32x4){0.f, 0.f, 0.f, 0.f};
  float zacc[4] = {0.f, 0.f, 0.f, 0.f};

  // prefetch chunk g
  float4 pf[4];
  float ppf = 0.f;
  {
    const float4* src = (const float4*)(slot + (size_t)g * 64 * K_);
#pragma unroll
    for (int i = 0; i < 4; ++i) pf[i] = src[tid + 256 * i];
    if (tid < 64) ppf = prio[g * 64 + tid];
  }

  for (int chunk = g; chunk < NCHUNK; chunk += G) {
    __syncthreads();
    // ---- stage: fp16 row-major (pad 72) for GEMM1 A; bf16 swizzled ^T ----
#pragma unroll
    for (int i = 0; i < 4; ++i) {
      const int f   = tid + 256 * i;
      const int row = f >> 4;
      const int c4  = (f & 15) * 4;
      float xs[4] = {pf[i].x, pf[i].y, pf[i].z, pf[i].w};
      unsigned hh[4];
#pragma unroll
      for (int j = 0; j < 4; ++j) {
        hh[j] = f2h(xs[j]);
        const int k = c4 + j;
        sh_T[k * 64 + (row ^ (p8hash(k) << 3))] =
            (unsigned short)f2bf(xs[j]);
      }
      *(uint2*)&sh_h[row * 72 + c4] =
          make_uint2(hh[0] | (hh[1] << 16), hh[2] | (hh[3] << 16));
    }
    if (tid < 64) sh_p[tid] = ppf;
    __syncthreads();

    // ---- prefetch next chunk (overlaps compute) ----
    const int nxt = chunk + G;
    if (nxt < NCHUNK) {
      const float4* src = (const float4*)(slot + (size_t)nxt * 64 * K_);
#pragma unroll
      for (int i = 0; i < 4; ++i) pf[i] = src[tid + 256 * i];
      if (tid < 64) ppf = prio[nxt * 64 + tid];
    }

    // ---- per n-half: GEMM1 (2 tiles) + E, then GEMM2 for that half ----
#pragma unroll
    for (int h = 0; h < 2; ++h) {
#pragma unroll
      for (int tt = 0; tt < 2; ++tt) {
        const int t = h * 2 + tt;
        f32x4 cc[4];
#pragma unroll
        for (int bt = 0; bt < 4; ++bt) cc[bt] = (f32x4){0.f, 0.f, 0.f, 0.f};
#pragma unroll
        for (int s = 0; s < 2; ++s) {
          const int off = (t * 16 + c16) * 72 + s * 32 + q * 8;
          int4 ah = *(const int4*)&sh_h[off];
#pragma unroll
          for (int bt = 0; bt < 4; ++bt)
            cc[bt] = mfma16h(ah, qf[bt][s], cc[bt]);
        }
        const float4 p = *(const float4*)&sh_p[t * 16 + q * 4];
#pragma unroll
        for (int bt = 0; bt < 4; ++bt) {
          float e0 = __expf(cc[bt][0] - SHIFT_) * p.x;
          float e1 = __expf(cc[bt][1] - SHIFT_) * p.y;
          float e2 = __expf(cc[bt][2] - SHIFT_) * p.z;
          float e3 = __expf(cc[bt][3] - SHIFT_) * p.w;
          zacc[bt] += (e0 + e1) + (e2 + e3);
          *(uint2*)&sh_E[w * 2560 + (bt * 16 + c16) * 40 + tt * 16 + q * 4] =
              make_uint2(pack2(e0, e1), pack2(e2, e3));
        }
      }
      // GEMM2 half h: S[b][kout] += sum_{n in half} E[b][n]*slot[n][kout]
      int4 bT[4];
#pragma unroll
      for (int ct = 0; ct < 4; ++ct) {
        const int k = ct * 16 + c16;
        bT[ct] = *(const int4*)&sh_T[k * 64 +
                                     ((h * 32 + q * 8) ^ (p8hash(k) << 3))];
      }
#pragma unroll
      for (int bt = 0; bt < 4; ++bt) {
        int4 aE =
            *(const int4*)&sh_E[w * 2560 + (bt * 16 + c16) * 40 + q * 8];
#pragma unroll
        for (int ct = 0; ct < 4; ++ct)
          S[bt][ct] = mfma16b(aE, bT[ct], S[bt][ct]);
      }
    }
  }

  // ---- epilogue: stage S (bf16) into overlay [4][64][72], then stream ----
  __syncthreads();  // all chunk compute done; sh_all reusable
  unsigned short* const stg = sh_all;
#pragma unroll
  for (int bt = 0; bt < 4; ++bt) {
#pragma unroll
    for (int ct = 0; ct < 4; ++ct) {
#pragma unroll
      for (int r = 0; r < 4; ++r) {
        stg[(w * 64 + bt * 16 + q * 4 + r) * 72 + ct * 16 + c16] =
            (unsigned short)f2bf(S[bt][ct][r]);
      }
    }
  }
  __syncthreads();
#pragma unroll
  for (int i = 0; i < 8; ++i) {
    const int idx   = tid + 256 * i;
    const int batch = idx >> 3;
    const int seg   = idx & 7;
    uint4 v = *(const uint4*)&stg[batch * 72 + seg * 8];
    *(uint4*)&Spart[((size_t)batch * G + g) * K_ + seg * 8] = v;
  }
#pragma unroll
  for (int bt = 0; bt < 4; ++bt) {
    float z = zacc[bt];
    z += __shfl_xor(z, 16);
    z += __shfl_xor(z, 32);
    if (l < 16) Zpart[(size_t)(w * 64 + bt * 16 + c16) * G + g] = z;
  }
}

// ---------------------------------------------------------------------------
// K3a: block (b,s) reduces Spart g-slice -> rkpart[b][s][k]. (frozen)
// ---------------------------------------------------------------------------
__global__ __launch_bounds__(256) void k3a_reduce(
    const unsigned short* __restrict__ Spart, float* __restrict__ rkpart,
    int G) {
  const int b   = blockIdx.x;
  const int s   = blockIdx.y;
  const int tid = threadIdx.x;
  const int gq  = tid >> 3;
  const int k8  = tid & 7;

  __shared__ float part[32][65];

  const int gcnt = G / SL_;
  const int gbeg = s * gcnt;

  float acc[8] = {0.f, 0.f, 0.f, 0.f, 0.f, 0.f, 0.f, 0.f};
  const unsigned short* sp = Spart + (size_t)b * G * K_ + k8 * 8;
  for (int gg = gq; gg < gcnt; gg += 32) {
    uint4 v = *(const uint4*)(sp + (size_t)(gbeg + gg) * K_);
    acc[0] += __uint_as_float(v.x << 16);
    acc[1] += __uint_as_float(v.x & 0xffff0000u);
    acc[2] += __uint_as_float(v.y << 16);
    acc[3] += __uint_as_float(v.y & 0xffff0000u);
    acc[4] += __uint_as_float(v.z << 16);
    acc[5] += __uint_as_float(v.z & 0xffff0000u);
    acc[6] += __uint_as_float(v.w << 16);
    acc[7] += __uint_as_float(v.w & 0xffff0000u);
  }
#pragma unroll
  for (int j = 0; j < 8; ++j) part[gq][k8 * 8 + j] = acc[j];
  __syncthreads();

  if (tid < 64) {
    float sum = 0.f;
#pragma unroll
    for (int r = 0; r < 32; ++r) sum += part[r][tid];
    rkpart[((size_t)b * SL_ + s) * K_ + tid] = sum;
  }
}

// ---------------------------------------------------------------------------
// K3b: rk = (sum_s rkpart)/Z; decode via LDS-staged wdec tile. (frozen)
// ---------------------------------------------------------------------------
__global__ __launch_bounds__(256) void k3b_decode(
    const float* __restrict__ rkpart, const float* __restrict__ Zpart,
    const float* __restrict__ wdec, float* __restrict__ out, int G) {
  const int b   = blockIdx.x;
  const int j   = blockIdx.y;
  const int tid = threadIdx.x;

  __shared__ float zred[256];
  __shared__ float rk[K_];
  __shared__ float wlds[256 * 65];

  float zp = 0.f;
  const float* zpp = Zpart + (size_t)b * G;
  for (int g = tid; g < G; g += 256) zp += zpp[g];
  zred[tid] = zp;
  __syncthreads();

  if (tid < K_) {
    float ssum = 0.f;
#pragma unroll
    for (int s = 0; s < SL_; ++s)
      ssum += rkpart[((size_t)b * SL_ + s) * K_ + tid];
    if (tid == 0) {
      float zz = 0.f;
      for (int i = 0; i < 256; ++i) zz += zred[i];
      zred[0] = fmaxf(zz, 1e-30f);
    }
    rk[tid] = ssum;
  }
  __syncthreads();
  const float invZ = 1.0f / zred[0];

#pragma unroll
  for (int i = 0; i < 16; ++i) {
    const int f   = tid + 256 * i;
    const int row = f >> 4;
    const int c4  = (f & 15) * 4;
    const float4 v =
        *(const float4*)(wdec + (size_t)(j * 256 + row) * K_ + c4);
    wlds[row * 65 + c4 + 0] = v.x;
    wlds[row * 65 + c4 + 1] = v.y;
    wlds[row * 65 + c4 + 2] = v.z;
    wlds[row * 65 + c4 + 3] = v.w;
  }
  __syncthreads();

  float acc = 0.f;
#pragma unroll
  for (int kk = 0; kk < 64; ++kk) acc += rk[kk] * wlds[tid * 65 + kk];
  out[(size_t)b * D_ + j * 256 + tid] = acc * invZ;
}

// ---------------------------------------------------------------------------
extern "C" void kernel_launch(void* const* d_in, const int* in_sizes, int n_in,
                              void* d_out, int out_size, void* d_ws,
                              size_t ws_size, hipStream_t stream) {
  const float* cue  = (const float*)d_in[0];
  const float* slot = (const float*)d_in[1];
  const float* prio = (const float*)d_in[2];
  const float* wcue = (const float*)d_in[3];
  const float* wdec = (const float*)d_in[4];
  float* out = (float*)d_out;

  // ws: couter (64KB) | Spart bf16 [B][G][64] | Zpart fp32 [B][G] |
  //     rkpart fp32 [B][8][64] (512KB)
  const size_t per_g = (size_t)B_ * K_ * 2 + (size_t)B_ * 4;  // 33792 B
  long long avail = (long long)ws_size - 65536 - 524288;
  int G = (int)(avail > 0 ? avail / (long long)per_g : SL_);
  if (G > 1024) G = 1024;   // 4 blocks/CU co-resident
  G &= ~(SL_ - 1);          // K3a needs G % 8 == 0
  if (G < SL_) G = SL_;

  float* couter         = (float*)d_ws;
  unsigned short* Spart = (unsigned short*)(couter + 16384);
  float* Zpart          = (float*)(Spart + (size_t)B_ * G * K_);
  float* rkpart         = Zpart + (size_t)B_ * G;

  k1_cueproj<<<dim3(B_), dim3(256), 0, stream>>>(cue, wcue, couter);
  k2_attend<<<dim3(G), dim3(256), 0, stream>>>(slot, prio, couter, Spart,
                                               Zpart, G);
  k3a_reduce<<<dim3(B_, SL_), dim3(256), 0, stream>>>(Spart, rkpart, G);
  k3b_decode<<<dim3(B_, 4), dim3(256), 0, stream>>>(rkpart, Zpart, wdec, out,
                                                    G);
}

// Round 11
// 141.142 us; speedup vs baseline: 2.3407x; 2.3407x over previous
//
#include <hip/hip_runtime.h>
#include <hip/hip_fp16.h>

#define B_ 256
#define D_ 1024
#define N_ 200000
#define K_ 64
#define SHIFT_ 24.0f
#define NCHUNK 3125   // N_/64 exactly
#define SL_ 8         // K3a G-slices

typedef short short8 __attribute__((ext_vector_type(8)));
typedef _Float16 f16x8 __attribute__((ext_vector_type(8)));
typedef float f32x4 __attribute__((ext_vector_type(4)));

__device__ __forceinline__ unsigned f2bf(float x) {
  unsigned u = __float_as_uint(x);
  return (u + 0x7fffu + ((u >> 16) & 1u)) >> 16;
}
__device__ __forceinline__ unsigned pack2(float a, float b) {
  return f2bf(a) | (f2bf(b) << 16);
}
__device__ __forceinline__ float bf2f(unsigned short u) {
  return __uint_as_float(((unsigned)u) << 16);
}
__device__ __forceinline__ unsigned f2h(float x) {  // fp16 bits, RNE
  return (unsigned)__half_as_ushort(__float2half(x));
}
__device__ __forceinline__ f32x4 mfma16b(int4 a, int4 b, f32x4 c) {  // bf16
  return __builtin_amdgcn_mfma_f32_16x16x32_bf16(
      __builtin_bit_cast(short8, a), __builtin_bit_cast(short8, b), c, 0, 0, 0);
}
__device__ __forceinline__ f32x4 mfma16h(int4 a, int4 b, f32x4 c) {  // fp16
  return __builtin_amdgcn_mfma_f32_16x16x32_f16(
      __builtin_bit_cast(f16x8, a), __builtin_bit_cast(f16x8, b), c, 0, 0, 0);
}
__device__ __forceinline__ int p8hash(int k) { return ((k >> 3) ^ k) & 7; }

// ---------------------------------------------------------------------------
// K1: cue_outer[b][k] = sum_d cue[b][d] * w_cue[k][d]  (frozen)
// ---------------------------------------------------------------------------
__global__ __launch_bounds__(256) void k1_cueproj(
    const float* __restrict__ cue, const float* __restrict__ wcue,
    float* __restrict__ couter) {
  const int b    = blockIdx.x;
  const int tid  = threadIdx.x;
  const int w    = tid >> 6;
  const int lane = tid & 63;

  __shared__ float part[4][64][65];
  __shared__ float red[4][64];

  const float4 creg =
      *(const float4*)(cue + (size_t)b * D_ + w * 256 + lane * 4);
  const float* wbase = wcue + w * 256 + lane * 4;

#pragma unroll 8
  for (int k = 0; k < 64; ++k) {
    const float4 wv = *(const float4*)(wbase + (size_t)k * D_);
    part[w][k][lane] =
        creg.x * wv.x + creg.y * wv.y + creg.z * wv.z + creg.w * wv.w;
  }
  __syncthreads();

  const int k  = tid & 63;
  const int wq = tid >> 6;
  float a = 0.f;
#pragma unroll 8
  for (int j = 0; j < 64; ++j) a += part[wq][k][j];
  red[wq][k] = a;
  __syncthreads();
  if (tid < 64) {
    couter[b * K_ + tid] =
        red[0][tid] + red[1][tid] + red[2][tid] + red[3][tid];
  }
}

// ---------------------------------------------------------------------------
// K2: MFMA flash-attention. 38.4 KB LDS union (4 blocks/CU by LDS); launch
// bounds (256,2) -> VGPR cap 256: compiler lands ~128 (R8-proven), NO spills.
// (R10's (256,4) forced VGPR<=128->64 and spilled the accumulators: 660 MB
// of scratch traffic. The 2nd arg is a hard VGPR budget - never force it
// below the kernel's live set.)
// ---------------------------------------------------------------------------
__global__ __launch_bounds__(256, 2) void k2_attend(
    const float* __restrict__ slot, const float* __restrict__ prio,
    const float* __restrict__ couter, unsigned short* __restrict__ Spart,
    float* __restrict__ Zpart, int G) {
  // union: sh_h[64*72] | sh_T[64*64] | sh_E[4][64*40] | sh_p[64]  = 38400 B
  // epilogue staging view: [4][64][72] = 36864 B (overlays everything)
  __shared__ __align__(16) unsigned short sh_all[19200];
  unsigned short* const sh_h = sh_all;           // 4608 shorts
  unsigned short* const sh_T = sh_all + 4608;    // 4096 shorts
  unsigned short* const sh_E = sh_all + 8704;    // 10240 shorts (4 x 2560)
  float* const sh_p = (float*)(sh_all + 18944);  // 64 floats

  const int tid = threadIdx.x;
  const int g   = blockIdx.x;
  const int l   = tid & 63;
  const int w   = tid >> 6;
  const int c16 = l & 15;
  const int q   = l >> 4;

  // Q fragments (fp16), loaded once
  int4 qf[4][2];
#pragma unroll
  for (int bt = 0; bt < 4; ++bt) {
#pragma unroll
    for (int s = 0; s < 2; ++s) {
      const float* qp =
          couter + (size_t)(w * 64 + bt * 16 + c16) * K_ + s * 32 + q * 8;
      float4 va = *(const float4*)qp;
      float4 vb = *(const float4*)(qp + 4);
      qf[bt][s] = make_int4(
          (int)(f2h(va.x) | (f2h(va.y) << 16)),
          (int)(f2h(va.z) | (f2h(va.w) << 16)),
          (int)(f2h(vb.x) | (f2h(vb.y) << 16)),
          (int)(f2h(vb.z) | (f2h(vb.w) << 16)));
    }
  }

  f32x4 S[4][4];
#pragma unroll
  for (int a = 0; a < 4; ++a)
#pragma unroll
    for (int b = 0; b < 4; ++b) S[a][b] = (f32x4){0.f, 0.f, 0.f, 0.f};
  float zacc[4] = {0.f, 0.f, 0.f, 0.f};

  // prefetch chunk g
  float4 pf[4];
  float ppf = 0.f;
  {
    const float4* src = (const float4*)(slot + (size_t)g * 64 * K_);
#pragma unroll
    for (int i = 0; i < 4; ++i) pf[i] = src[tid + 256 * i];
    if (tid < 64) ppf = prio[g * 64 + tid];
  }

  for (int chunk = g; chunk < NCHUNK; chunk += G) {
    __syncthreads();
    // ---- stage: fp16 row-major (pad 72) for GEMM1 A; bf16 swizzled ^T ----
#pragma unroll
    for (int i = 0; i < 4; ++i) {
      const int f   = tid + 256 * i;
      const int row = f >> 4;
      const int c4  = (f & 15) * 4;
      float xs[4] = {pf[i].x, pf[i].y, pf[i].z, pf[i].w};
      unsigned hh[4];
#pragma unroll
      for (int j = 0; j < 4; ++j) {
        hh[j] = f2h(xs[j]);
        const int k = c4 + j;
        sh_T[k * 64 + (row ^ (p8hash(k) << 3))] =
            (unsigned short)f2bf(xs[j]);
      }
      *(uint2*)&sh_h[row * 72 + c4] =
          make_uint2(hh[0] | (hh[1] << 16), hh[2] | (hh[3] << 16));
    }
    if (tid < 64) sh_p[tid] = ppf;
    __syncthreads();

    // ---- prefetch next chunk (overlaps compute) ----
    const int nxt = chunk + G;
    if (nxt < NCHUNK) {
      const float4* src = (const float4*)(slot + (size_t)nxt * 64 * K_);
#pragma unroll
      for (int i = 0; i < 4; ++i) pf[i] = src[tid + 256 * i];
      if (tid < 64) ppf = prio[nxt * 64 + tid];
    }

    // ---- per n-half: GEMM1 (2 tiles) + E, then GEMM2 for that half ----
#pragma unroll
    for (int h = 0; h < 2; ++h) {
#pragma unroll
      for (int tt = 0; tt < 2; ++tt) {
        const int t = h * 2 + tt;
        f32x4 cc[4];
#pragma unroll
        for (int bt = 0; bt < 4; ++bt) cc[bt] = (f32x4){0.f, 0.f, 0.f, 0.f};
#pragma unroll
        for (int s = 0; s < 2; ++s) {
          const int off = (t * 16 + c16) * 72 + s * 32 + q * 8;
          int4 ah = *(const int4*)&sh_h[off];
#pragma unroll
          for (int bt = 0; bt < 4; ++bt)
            cc[bt] = mfma16h(ah, qf[bt][s], cc[bt]);
        }
        const float4 p = *(const float4*)&sh_p[t * 16 + q * 4];
#pragma unroll
        for (int bt = 0; bt < 4; ++bt) {
          float e0 = __expf(cc[bt][0] - SHIFT_) * p.x;
          float e1 = __expf(cc[bt][1] - SHIFT_) * p.y;
          float e2 = __expf(cc[bt][2] - SHIFT_) * p.z;
          float e3 = __expf(cc[bt][3] - SHIFT_) * p.w;
          zacc[bt] += (e0 + e1) + (e2 + e3);
          *(uint2*)&sh_E[w * 2560 + (bt * 16 + c16) * 40 + tt * 16 + q * 4] =
              make_uint2(pack2(e0, e1), pack2(e2, e3));
        }
      }
      // GEMM2 half h: S[b][kout] += sum_{n in half} E[b][n]*slot[n][kout]
      int4 bT[4];
#pragma unroll
      for (int ct = 0; ct < 4; ++ct) {
        const int k = ct * 16 + c16;
        bT[ct] = *(const int4*)&sh_T[k * 64 +
                                     ((h * 32 + q * 8) ^ (p8hash(k) << 3))];
      }
#pragma unroll
      for (int bt = 0; bt < 4; ++bt) {
        int4 aE =
            *(const int4*)&sh_E[w * 2560 + (bt * 16 + c16) * 40 + q * 8];
#pragma unroll
        for (int ct = 0; ct < 4; ++ct)
          S[bt][ct] = mfma16b(aE, bT[ct], S[bt][ct]);
      }
    }
  }

  // ---- epilogue: stage S (bf16) into overlay [4][64][72], then stream ----
  __syncthreads();  // all chunk compute done; sh_all reusable
  unsigned short* const stg = sh_all;
#pragma unroll
  for (int bt = 0; bt < 4; ++bt) {
#pragma unroll
    for (int ct = 0; ct < 4; ++ct) {
#pragma unroll
      for (int r = 0; r < 4; ++r) {
        stg[(w * 64 + bt * 16 + q * 4 + r) * 72 + ct * 16 + c16] =
            (unsigned short)f2bf(S[bt][ct][r]);
      }
    }
  }
  __syncthreads();
#pragma unroll
  for (int i = 0; i < 8; ++i) {
    const int idx   = tid + 256 * i;
    const int batch = idx >> 3;
    const int seg   = idx & 7;
    uint4 v = *(const uint4*)&stg[batch * 72 + seg * 8];
    *(uint4*)&Spart[((size_t)batch * G + g) * K_ + seg * 8] = v;
  }
#pragma unroll
  for (int bt = 0; bt < 4; ++bt) {
    float z = zacc[bt];
    z += __shfl_xor(z, 16);
    z += __shfl_xor(z, 32);
    if (l < 16) Zpart[(size_t)(w * 64 + bt * 16 + c16) * G + g] = z;
  }
}

// ---------------------------------------------------------------------------
// K3a: block (b,s) reduces Spart g-slice -> rkpart[b][s][k]. (frozen)
// ---------------------------------------------------------------------------
__global__ __launch_bounds__(256) void k3a_reduce(
    const unsigned short* __restrict__ Spart, float* __restrict__ rkpart,
    int G) {
  const int b   = blockIdx.x;
  const int s   = blockIdx.y;
  const int tid = threadIdx.x;
  const int gq  = tid >> 3;
  const int k8  = tid & 7;

  __shared__ float part[32][65];

  const int gcnt = G / SL_;
  const int gbeg = s * gcnt;

  float acc[8] = {0.f, 0.f, 0.f, 0.f, 0.f, 0.f, 0.f, 0.f};
  const unsigned short* sp = Spart + (size_t)b * G * K_ + k8 * 8;
  for (int gg = gq; gg < gcnt; gg += 32) {
    uint4 v = *(const uint4*)(sp + (size_t)(gbeg + gg) * K_);
    acc[0] += __uint_as_float(v.x << 16);
    acc[1] += __uint_as_float(v.x & 0xffff0000u);
    acc[2] += __uint_as_float(v.y << 16);
    acc[3] += __uint_as_float(v.y & 0xffff0000u);
    acc[4] += __uint_as_float(v.z << 16);
    acc[5] += __uint_as_float(v.z & 0xffff0000u);
    acc[6] += __uint_as_float(v.w << 16);
    acc[7] += __uint_as_float(v.w & 0xffff0000u);
  }
#pragma unroll
  for (int j = 0; j < 8; ++j) part[gq][k8 * 8 + j] = acc[j];
  __syncthreads();

  if (tid < 64) {
    float sum = 0.f;
#pragma unroll
    for (int r = 0; r < 32; ++r) sum += part[r][tid];
    rkpart[((size_t)b * SL_ + s) * K_ + tid] = sum;
  }
}

// ---------------------------------------------------------------------------
// K3b: rk = (sum_s rkpart)/Z; decode via LDS-staged wdec tile. (frozen)
// ---------------------------------------------------------------------------
__global__ __launch_bounds__(256) void k3b_decode(
    const float* __restrict__ rkpart, const float* __restrict__ Zpart,
    const float* __restrict__ wdec, float* __restrict__ out, int G) {
  const int b   = blockIdx.x;
  const int j   = blockIdx.y;
  const int tid = threadIdx.x;

  __shared__ float zred[256];
  __shared__ float rk[K_];
  __shared__ float wlds[256 * 65];

  float zp = 0.f;
  const float* zpp = Zpart + (size_t)b * G;
  for (int g = tid; g < G; g += 256) zp += zpp[g];
  zred[tid] = zp;
  __syncthreads();

  if (tid < K_) {
    float ssum = 0.f;
#pragma unroll
    for (int s = 0; s < SL_; ++s)
      ssum += rkpart[((size_t)b * SL_ + s) * K_ + tid];
    if (tid == 0) {
      float zz = 0.f;
      for (int i = 0; i < 256; ++i) zz += zred[i];
      zred[0] = fmaxf(zz, 1e-30f);
    }
    rk[tid] = ssum;
  }
  __syncthreads();
  const float invZ = 1.0f / zred[0];

#pragma unroll
  for (int i = 0; i < 16; ++i) {
    const int f   = tid + 256 * i;
    const int row = f >> 4;
    const int c4  = (f & 15) * 4;
    const float4 v =
        *(const float4*)(wdec + (size_t)(j * 256 + row) * K_ + c4);
    wlds[row * 65 + c4 + 0] = v.x;
    wlds[row * 65 + c4 + 1] = v.y;
    wlds[row * 65 + c4 + 2] = v.z;
    wlds[row * 65 + c4 + 3] = v.w;
  }
  __syncthreads();

  float acc = 0.f;
#pragma unroll
  for (int kk = 0; kk < 64; ++kk) acc += rk[kk] * wlds[tid * 65 + kk];
  out[(size_t)b * D_ + j * 256 + tid] = acc * invZ;
}

// ---------------------------------------------------------------------------
extern "C" void kernel_launch(void* const* d_in, const int* in_sizes, int n_in,
                              void* d_out, int out_size, void* d_ws,
                              size_t ws_size, hipStream_t stream) {
  const float* cue  = (const float*)d_in[0];
  const float* slot = (const float*)d_in[1];
  const float* prio = (const float*)d_in[2];
  const float* wcue = (const float*)d_in[3];
  const float* wdec = (const float*)d_in[4];
  float* out = (float*)d_out;

  // ws: couter (64KB) | Spart bf16 [B][G][64] | Zpart fp32 [B][G] |
  //     rkpart fp32 [B][8][64] (512KB)
  const size_t per_g = (size_t)B_ * K_ * 2 + (size_t)B_ * 4;  // 33792 B
  long long avail = (long long)ws_size - 65536 - 524288;
  int G = (int)(avail > 0 ? avail / (long long)per_g : SL_);
  if (G > 1024) G = 1024;   // 4 blocks/CU co-resident (LDS 38.4KB, VGPR~128)
  G &= ~(SL_ - 1);          // K3a needs G % 8 == 0
  if (G < SL_) G = SL_;

  float* couter         = (float*)d_ws;
  unsigned short* Spart = (unsigned short*)(couter + 16384);
  float* Zpart          = (float*)(Spart + (size_t)B_ * G * K_);
  float* rkpart         = Zpart + (size_t)B_ * G;

  k1_cueproj<<<dim3(B_), dim3(256), 0, stream>>>(cue, wcue, couter);
  k2_attend<<<dim3(G), dim3(256), 0, stream>>>(slot, prio, couter, Spart,
                                               Zpart, G);
  k3a_reduce<<<dim3(B_, SL_), dim3(256), 0, stream>>>(Spart, rkpart, G);
  k3b_decode<<<dim3(B_, 4), dim3(256), 0, stream>>>(rkpart, Zpart, wdec, out,
                                                    G);
}

// Round 12
// 133.337 us; speedup vs baseline: 2.4777x; 1.0585x over previous
//
#include <hip/hip_runtime.h>
#include <hip/hip_fp16.h>

#define B_ 256
#define D_ 1024
#define N_ 200000
#define K_ 64
#define SHIFT_ 24.0f
#define NCHUNK 3125   // N_/64 exactly
#define SL_ 8         // K3a G-slices

typedef short short8 __attribute__((ext_vector_type(8)));
typedef _Float16 f16x8 __attribute__((ext_vector_type(8)));
typedef float f32x4 __attribute__((ext_vector_type(4)));

__device__ __forceinline__ unsigned f2bf(float x) {
  unsigned u = __float_as_uint(x);
  return (u + 0x7fffu + ((u >> 16) & 1u)) >> 16;
}
__device__ __forceinline__ unsigned pack2(float a, float b) {
  return f2bf(a) | (f2bf(b) << 16);
}
__device__ __forceinline__ float bf2f(unsigned short u) {
  return __uint_as_float(((unsigned)u) << 16);
}
__device__ __forceinline__ unsigned f2h(float x) {  // fp16 bits, RNE
  return (unsigned)__half_as_ushort(__float2half(x));
}
__device__ __forceinline__ f32x4 mfma16b(int4 a, int4 b, f32x4 c) {  // bf16
  return __builtin_amdgcn_mfma_f32_16x16x32_bf16(
      __builtin_bit_cast(short8, a), __builtin_bit_cast(short8, b), c, 0, 0, 0);
}
__device__ __forceinline__ f32x4 mfma16h(int4 a, int4 b, f32x4 c) {  // fp16
  return __builtin_amdgcn_mfma_f32_16x16x32_f16(
      __builtin_bit_cast(f16x8, a), __builtin_bit_cast(f16x8, b), c, 0, 0, 0);
}
__device__ __forceinline__ int p8hash(int k) { return ((k >> 3) ^ k) & 7; }

// ---------------------------------------------------------------------------
// K1: cue_outer[b][k] = sum_d cue[b][d] * w_cue[k][d]  (frozen)
// ---------------------------------------------------------------------------
__global__ __launch_bounds__(256) void k1_cueproj(
    const float* __restrict__ cue, const float* __restrict__ wcue,
    float* __restrict__ couter) {
  const int b    = blockIdx.x;
  const int tid  = threadIdx.x;
  const int w    = tid >> 6;
  const int lane = tid & 63;

  __shared__ float part[4][64][65];
  __shared__ float red[4][64];

  const float4 creg =
      *(const float4*)(cue + (size_t)b * D_ + w * 256 + lane * 4);
  const float* wbase = wcue + w * 256 + lane * 4;

#pragma unroll 8
  for (int k = 0; k < 64; ++k) {
    const float4 wv = *(const float4*)(wbase + (size_t)k * D_);
    part[w][k][lane] =
        creg.x * wv.x + creg.y * wv.y + creg.z * wv.z + creg.w * wv.w;
  }
  __syncthreads();

  const int k  = tid & 63;
  const int wq = tid >> 6;
  float a = 0.f;
#pragma unroll 8
  for (int j = 0; j < 64; ++j) a += part[wq][k][j];
  red[wq][k] = a;
  __syncthreads();
  if (tid < 64) {
    couter[b * K_ + tid] =
        red[0][tid] + red[1][tid] + red[2][tid] + red[3][tid];
  }
}

// ---------------------------------------------------------------------------
// K2: MFMA flash-attention. R11's diet loop (38.4 KB LDS union, (256,2),
// VGPR ~128, 4 blocks/CU) but at G=512: 6.1 chunks/block re-amortizes the
// epilogue and halves Spart traffic vs R11's G=1024.
// ---------------------------------------------------------------------------
__global__ __launch_bounds__(256, 2) void k2_attend(
    const float* __restrict__ slot, const float* __restrict__ prio,
    const float* __restrict__ couter, unsigned short* __restrict__ Spart,
    float* __restrict__ Zpart, int G) {
  // union: sh_h[64*72] | sh_T[64*64] | sh_E[4][64*40] | sh_p[64]  = 38400 B
  // epilogue staging view: [4][64][72] = 36864 B (overlays everything)
  __shared__ __align__(16) unsigned short sh_all[19200];
  unsigned short* const sh_h = sh_all;           // 4608 shorts
  unsigned short* const sh_T = sh_all + 4608;    // 4096 shorts
  unsigned short* const sh_E = sh_all + 8704;    // 10240 shorts (4 x 2560)
  float* const sh_p = (float*)(sh_all + 18944);  // 64 floats

  const int tid = threadIdx.x;
  const int g   = blockIdx.x;
  const int l   = tid & 63;
  const int w   = tid >> 6;
  const int c16 = l & 15;
  const int q   = l >> 4;

  // Q fragments (fp16), loaded once
  int4 qf[4][2];
#pragma unroll
  for (int bt = 0; bt < 4; ++bt) {
#pragma unroll
    for (int s = 0; s < 2; ++s) {
      const float* qp =
          couter + (size_t)(w * 64 + bt * 16 + c16) * K_ + s * 32 + q * 8;
      float4 va = *(const float4*)qp;
      float4 vb = *(const float4*)(qp + 4);
      qf[bt][s] = make_int4(
          (int)(f2h(va.x) | (f2h(va.y) << 16)),
          (int)(f2h(va.z) | (f2h(va.w) << 16)),
          (int)(f2h(vb.x) | (f2h(vb.y) << 16)),
          (int)(f2h(vb.z) | (f2h(vb.w) << 16)));
    }
  }

  f32x4 S[4][4];
#pragma unroll
  for (int a = 0; a < 4; ++a)
#pragma unroll
    for (int b = 0; b < 4; ++b) S[a][b] = (f32x4){0.f, 0.f, 0.f, 0.f};
  float zacc[4] = {0.f, 0.f, 0.f, 0.f};

  // prefetch chunk g
  float4 pf[4];
  float ppf = 0.f;
  {
    const float4* src = (const float4*)(slot + (size_t)g * 64 * K_);
#pragma unroll
    for (int i = 0; i < 4; ++i) pf[i] = src[tid + 256 * i];
    if (tid < 64) ppf = prio[g * 64 + tid];
  }

  for (int chunk = g; chunk < NCHUNK; chunk += G) {
    __syncthreads();
    // ---- stage: fp16 row-major (pad 72) for GEMM1 A; bf16 swizzled ^T ----
#pragma unroll
    for (int i = 0; i < 4; ++i) {
      const int f   = tid + 256 * i;
      const int row = f >> 4;
      const int c4  = (f & 15) * 4;
      float xs[4] = {pf[i].x, pf[i].y, pf[i].z, pf[i].w};
      unsigned hh[4];
#pragma unroll
      for (int j = 0; j < 4; ++j) {
        hh[j] = f2h(xs[j]);
        const int k = c4 + j;
        sh_T[k * 64 + (row ^ (p8hash(k) << 3))] =
            (unsigned short)f2bf(xs[j]);
      }
      *(uint2*)&sh_h[row * 72 + c4] =
          make_uint2(hh[0] | (hh[1] << 16), hh[2] | (hh[3] << 16));
    }
    if (tid < 64) sh_p[tid] = ppf;
    __syncthreads();

    // ---- prefetch next chunk (overlaps compute) ----
    const int nxt = chunk + G;
    if (nxt < NCHUNK) {
      const float4* src = (const float4*)(slot + (size_t)nxt * 64 * K_);
#pragma unroll
      for (int i = 0; i < 4; ++i) pf[i] = src[tid + 256 * i];
      if (tid < 64) ppf = prio[nxt * 64 + tid];
    }

    // ---- per n-half: GEMM1 (2 tiles) + E, then GEMM2 for that half ----
#pragma unroll
    for (int h = 0; h < 2; ++h) {
#pragma unroll
      for (int tt = 0; tt < 2; ++tt) {
        const int t = h * 2 + tt;
        f32x4 cc[4];
#pragma unroll
        for (int bt = 0; bt < 4; ++bt) cc[bt] = (f32x4){0.f, 0.f, 0.f, 0.f};
#pragma unroll
        for (int s = 0; s < 2; ++s) {
          const int off = (t * 16 + c16) * 72 + s * 32 + q * 8;
          int4 ah = *(const int4*)&sh_h[off];
#pragma unroll
          for (int bt = 0; bt < 4; ++bt)
            cc[bt] = mfma16h(ah, qf[bt][s], cc[bt]);
        }
        const float4 p = *(const float4*)&sh_p[t * 16 + q * 4];
#pragma unroll
        for (int bt = 0; bt < 4; ++bt) {
          float e0 = __expf(cc[bt][0] - SHIFT_) * p.x;
          float e1 = __expf(cc[bt][1] - SHIFT_) * p.y;
          float e2 = __expf(cc[bt][2] - SHIFT_) * p.z;
          float e3 = __expf(cc[bt][3] - SHIFT_) * p.w;
          zacc[bt] += (e0 + e1) + (e2 + e3);
          *(uint2*)&sh_E[w * 2560 + (bt * 16 + c16) * 40 + tt * 16 + q * 4] =
              make_uint2(pack2(e0, e1), pack2(e2, e3));
        }
      }
      // GEMM2 half h: S[b][kout] += sum_{n in half} E[b][n]*slot[n][kout]
      int4 bT[4];
#pragma unroll
      for (int ct = 0; ct < 4; ++ct) {
        const int k = ct * 16 + c16;
        bT[ct] = *(const int4*)&sh_T[k * 64 +
                                     ((h * 32 + q * 8) ^ (p8hash(k) << 3))];
      }
#pragma unroll
      for (int bt = 0; bt < 4; ++bt) {
        int4 aE =
            *(const int4*)&sh_E[w * 2560 + (bt * 16 + c16) * 40 + q * 8];
#pragma unroll
        for (int ct = 0; ct < 4; ++ct)
          S[bt][ct] = mfma16b(aE, bT[ct], S[bt][ct]);
      }
    }
  }

  // ---- epilogue: stage S (bf16) into overlay [4][64][72], then stream ----
  __syncthreads();  // all chunk compute done; sh_all reusable
  unsigned short* const stg = sh_all;
#pragma unroll
  for (int bt = 0; bt < 4; ++bt) {
#pragma unroll
    for (int ct = 0; ct < 4; ++ct) {
#pragma unroll
      for (int r = 0; r < 4; ++r) {
        stg[(w * 64 + bt * 16 + q * 4 + r) * 72 + ct * 16 + c16] =
            (unsigned short)f2bf(S[bt][ct][r]);
      }
    }
  }
  __syncthreads();
#pragma unroll
  for (int i = 0; i < 8; ++i) {
    const int idx   = tid + 256 * i;
    const int batch = idx >> 3;
    const int seg   = idx & 7;
    uint4 v = *(const uint4*)&stg[batch * 72 + seg * 8];
    *(uint4*)&Spart[((size_t)batch * G + g) * K_ + seg * 8] = v;
  }
#pragma unroll
  for (int bt = 0; bt < 4; ++bt) {
    float z = zacc[bt];
    z += __shfl_xor(z, 16);
    z += __shfl_xor(z, 32);
    if (l < 16) Zpart[(size_t)(w * 64 + bt * 16 + c16) * G + g] = z;
  }
}

// ---------------------------------------------------------------------------
// K3a: block (b,s) reduces Spart g-slice -> rkpart[b][s][k]. (frozen)
// ---------------------------------------------------------------------------
__global__ __launch_bounds__(256) void k3a_reduce(
    const unsigned short* __restrict__ Spart, float* __restrict__ rkpart,
    int G) {
  const int b   = blockIdx.x;
  const int s   = blockIdx.y;
  const int tid = threadIdx.x;
  const int gq  = tid >> 3;
  const int k8  = tid & 7;

  __shared__ float part[32][65];

  const int gcnt = G / SL_;
  const int gbeg = s * gcnt;

  float acc[8] = {0.f, 0.f, 0.f, 0.f, 0.f, 0.f, 0.f, 0.f};
  const unsigned short* sp = Spart + (size_t)b * G * K_ + k8 * 8;
  for (int gg = gq; gg < gcnt; gg += 32) {
    uint4 v = *(const uint4*)(sp + (size_t)(gbeg + gg) * K_);
    acc[0] += __uint_as_float(v.x << 16);
    acc[1] += __uint_as_float(v.x & 0xffff0000u);
    acc[2] += __uint_as_float(v.y << 16);
    acc[3] += __uint_as_float(v.y & 0xffff0000u);
    acc[4] += __uint_as_float(v.z << 16);
    acc[5] += __uint_as_float(v.z & 0xffff0000u);
    acc[6] += __uint_as_float(v.w << 16);
    acc[7] += __uint_as_float(v.w & 0xffff0000u);
  }
#pragma unroll
  for (int j = 0; j < 8; ++j) part[gq][k8 * 8 + j] = acc[j];
  __syncthreads();

  if (tid < 64) {
    float sum = 0.f;
#pragma unroll
    for (int r = 0; r < 32; ++r) sum += part[r][tid];
    rkpart[((size_t)b * SL_ + s) * K_ + tid] = sum;
  }
}

// ---------------------------------------------------------------------------
// K3b: rk = (sum_s rkpart)/Z; decode via LDS-staged wdec tile. (frozen)
// ---------------------------------------------------------------------------
__global__ __launch_bounds__(256) void k3b_decode(
    const float* __restrict__ rkpart, const float* __restrict__ Zpart,
    const float* __restrict__ wdec, float* __restrict__ out, int G) {
  const int b   = blockIdx.x;
  const int j   = blockIdx.y;
  const int tid = threadIdx.x;

  __shared__ float zred[256];
  __shared__ float rk[K_];
  __shared__ float wlds[256 * 65];

  float zp = 0.f;
  const float* zpp = Zpart + (size_t)b * G;
  for (int g = tid; g < G; g += 256) zp += zpp[g];
  zred[tid] = zp;
  __syncthreads();

  if (tid < K_) {
    float ssum = 0.f;
#pragma unroll
    for (int s = 0; s < SL_; ++s)
      ssum += rkpart[((size_t)b * SL_ + s) * K_ + tid];
    if (tid == 0) {
      float zz = 0.f;
      for (int i = 0; i < 256; ++i) zz += zred[i];
      zred[0] = fmaxf(zz, 1e-30f);
    }
    rk[tid] = ssum;
  }
  __syncthreads();
  const float invZ = 1.0f / zred[0];

#pragma unroll
  for (int i = 0; i < 16; ++i) {
    const int f   = tid + 256 * i;
    const int row = f >> 4;
    const int c4  = (f & 15) * 4;
    const float4 v =
        *(const float4*)(wdec + (size_t)(j * 256 + row) * K_ + c4);
    wlds[row * 65 + c4 + 0] = v.x;
    wlds[row * 65 + c4 + 1] = v.y;
    wlds[row * 65 + c4 + 2] = v.z;
    wlds[row * 65 + c4 + 3] = v.w;
  }
  __syncthreads();

  float acc = 0.f;
#pragma unroll
  for (int kk = 0; kk < 64; ++kk) acc += rk[kk] * wlds[tid * 65 + kk];
  out[(size_t)b * D_ + j * 256 + tid] = acc * invZ;
}

// ---------------------------------------------------------------------------
extern "C" void kernel_launch(void* const* d_in, const int* in_sizes, int n_in,
                              void* d_out, int out_size, void* d_ws,
                              size_t ws_size, hipStream_t stream) {
  const float* cue  = (const float*)d_in[0];
  const float* slot = (const float*)d_in[1];
  const float* prio = (const float*)d_in[2];
  const float* wcue = (const float*)d_in[3];
  const float* wdec = (const float*)d_in[4];
  float* out = (float*)d_out;

  // ws: couter (64KB) | Spart bf16 [B][G][64] | Zpart fp32 [B][G] |
  //     rkpart fp32 [B][8][64] (512KB)
  const size_t per_g = (size_t)B_ * K_ * 2 + (size_t)B_ * 4;  // 33792 B
  long long avail = (long long)ws_size - 65536 - 524288;
  int G = (int)(avail > 0 ? avail / (long long)per_g : SL_);
  if (G > 512) G = 512;     // back to R9's G: 6.1 chunks/block, 16.8MB Spart
  G &= ~(SL_ - 1);          // K3a needs G % 8 == 0
  if (G < SL_) G = SL_;

  float* couter         = (float*)d_ws;
  unsigned short* Spart = (unsigned short*)(couter + 16384);
  float* Zpart          = (float*)(Spart + (size_t)B_ * G * K_);
  float* rkpart         = Zpart + (size_t)B_ * G;

  k1_cueproj<<<dim3(B_), dim3(256), 0, stream>>>(cue, wcue, couter);
  k2_attend<<<dim3(G), dim3(256), 0, stream>>>(slot, prio, couter, Spart,
                                               Zpart, G);
  k3a_reduce<<<dim3(B_, SL_), dim3(256), 0, stream>>>(Spart, rkpart, G);
  k3b_decode<<<dim3(B_, 4), dim3(256), 0, stream>>>(rkpart, Zpart, wdec, out,
                                                    G);
}